// Round 1
// baseline (256.942 us; speedup 1.0000x reference)
//
#include <hip/hip_runtime.h>
#include <hip/hip_cooperative_groups.h>
#include <stdint.h>

namespace cg = cooperative_groups;

#define N 8192
#define D 256
#define NSUBJ 16
#define PADS 768                 // padded slot per subject (mean 512, +11 sigma safe)
#define GN (NSUBJ * PADS)        // 12288 gathered rows
#define MARGIN 1.0f
#define NBLK 512
#define NTHR 256
#define NTILES (NSUBJ * 12 * 12) // 2304 logical 64x64 tile-waves

typedef __attribute__((ext_vector_type(8))) short short8;   // 8 bf16 = 4 VGPRs (MFMA A/B frag)
typedef __attribute__((ext_vector_type(4))) float f32x4;    // MFMA C/D frag
typedef __attribute__((ext_vector_type(4))) unsigned short us4;
typedef unsigned long long u64;

__device__ __forceinline__ unsigned short f2bf(float x) {
    unsigned u = __float_as_uint(x);
    u += 0x7fffu + ((u >> 16) & 1u);
    return (unsigned short)(u >> 16);
}

// mining epilogue + main loop for one 64x64 tile (one wave). Identical math to
// the proven k_mine (bit-identical packed keys).
__device__ __forceinline__ void mine_tile(
        int s, int rowt, int ctile, int lane,
        const unsigned short* __restrict__ gH, const int* __restrict__ gIdx,
        const int* __restrict__ gLab, const float* __restrict__ gSq,
        const int* __restrict__ writePtr,
        u64* __restrict__ posP, u64* __restrict__ negP) {
    int quad = lane >> 4, l15 = lane & 15;
    int base = s * PADS;
    int cntS = writePtr[s] - base;
    if (rowt * 64 >= cntS || ctile * 64 >= cntS) return;   // wave-uniform exit
    int i0 = base + rowt * 64;
    int j0 = base + ctile * 64;

    int labc[4], idxc[4];
    float sqc[4];
    #pragma unroll
    for (int nt = 0; nt < 4; ++nt) {
        int c = j0 + nt * 16 + l15;
        labc[nt] = gLab[c]; idxc[nt] = gIdx[c]; sqc[nt] = gSq[c];
    }
    int labr[4][4], idxr[4][4];
    float sqr[4][4];
    #pragma unroll
    for (int mt = 0; mt < 4; ++mt)
        #pragma unroll
        for (int rg = 0; rg < 4; ++rg) {
            int r = i0 + mt * 16 + quad * 4 + rg;
            labr[mt][rg] = gLab[r]; idxr[mt][rg] = gIdx[r]; sqr[mt][rg] = gSq[r];
        }

    f32x4 acc[4][4];
    #pragma unroll
    for (int mt = 0; mt < 4; ++mt)
        #pragma unroll
        for (int nt = 0; nt < 4; ++nt) {
            f32x4 z = {0.f, 0.f, 0.f, 0.f};
            acc[mt][nt] = z;
        }

    #pragma unroll 2
    for (int kb = 0; kb < 8; ++kb) {
        int koff = kb * 32 + quad * 8;
        short8 a[4], b[4];
        #pragma unroll
        for (int mt = 0; mt < 4; ++mt)
            a[mt] = *(const short8*)(gH + (size_t)(i0 + mt * 16 + l15) * D + koff);
        #pragma unroll
        for (int nt = 0; nt < 4; ++nt)
            b[nt] = *(const short8*)(gH + (size_t)(j0 + nt * 16 + l15) * D + koff);
        #pragma unroll
        for (int mt = 0; mt < 4; ++mt)
            #pragma unroll
            for (int nt = 0; nt < 4; ++nt)
                acc[mt][nt] = __builtin_amdgcn_mfma_f32_16x16x32_bf16(
                    a[mt], b[nt], acc[mt][nt], 0, 0, 0);
    }

    #pragma unroll
    for (int mt = 0; mt < 4; ++mt) {
        u64 bp[4], bn[4];
        #pragma unroll
        for (int rg = 0; rg < 4; ++rg) { bp[rg] = 0ull; bn[rg] = ~0ull; }
        #pragma unroll
        for (int nt = 0; nt < 4; ++nt) {
            int lc = labc[nt], ic = idxc[nt];
            float sc = sqc[nt];
            f32x4 v = acc[mt][nt];
            #pragma unroll
            for (int rg = 0; rg < 4; ++rg) {
                float d2 = fmaxf(sqr[mt][rg] + sc - 2.0f * v[rg], 0.0f);
                u64 db = ((u64)__float_as_uint(d2)) << 32;
                if (lc == labr[mt][rg] && ic != idxr[mt][rg] && ic >= 0) {
                    u64 pk = db | (u64)(unsigned)(~(unsigned)ic);
                    if (pk > bp[rg]) bp[rg] = pk;
                }
                if (lc != labr[mt][rg] && ic >= 0) {
                    u64 nk = db | (u64)(unsigned)ic;
                    if (nk < bn[rg]) bn[rg] = nk;
                }
            }
        }
        #pragma unroll
        for (int o = 1; o < 16; o <<= 1) {
            #pragma unroll
            for (int rg = 0; rg < 4; ++rg) {
                u64 pp = __shfl_xor(bp[rg], o, 64);
                if (pp > bp[rg]) bp[rg] = pp;
                u64 qq = __shfl_xor(bn[rg], o, 64);
                if (qq < bn[rg]) bn[rg] = qq;
            }
        }
        if (l15 == 0) {
            #pragma unroll
            for (int rg = 0; rg < 4; ++rg) {
                int r = i0 + mt * 16 + quad * 4 + rg;
                if (bp[rg]) atomicMax(&posP[r], bp[rg]);
                if (bn[rg] != ~0ull) atomicMin(&negP[r], bn[rg]);
            }
        }
    }
}

// ---------------- fused cooperative kernel ----------------
// Phase A: 32 blocks/subject each scan sbjv up to their quarter-slice, extract
//          their rows' slots (bit-identical to the old sequential scan), and
//          gather/convert those rows; slice 31 writes the count + inits pads.
// Phase B: mining, 2304 logical tile-waves over 2048 physical waves.
// Phase C: block 0 reduces the loss, emulating the old 1024-thread order.
__global__ __launch_bounds__(NTHR, 2) void k_fused(
        const float* __restrict__ emb, const int* __restrict__ labels,
        const int* __restrict__ sbjv,
        unsigned short* __restrict__ gH, int* __restrict__ gIdx,
        int* __restrict__ gLab, float* __restrict__ gSq,
        int* __restrict__ writePtr, u64* __restrict__ posP,
        u64* __restrict__ negP, float* __restrict__ out) {
    cg::grid_group grid = cg::this_grid();
    int bid = blockIdx.x;
    int tid = threadIdx.x;
    int lane = tid & 63, w = tid >> 6;

    // ---------- Phase A ----------
    {
        int s = bid >> 5;               // subject 0..15
        int j = bid & 31;               // slice 0..31 (= it*4 + quarter)
        int q = j & 3;                  // which wave's 256-row quarter we own
        int itLim = j >> 2;             // scan only iterations 0..itLim

        __shared__ int wsum[4];
        __shared__ int lrow[256];
        __shared__ int lpos[256];
        __shared__ int nlist;

        int carry = s * PADS;           // uniform across threads
        for (int it = 0; it <= itLim; ++it) {
            int r0 = it * 1024 + tid * 4;
            int4 sv = *(const int4*)(sbjv + r0);
            int m0 = (sv.x == s), m1 = (sv.y == s), m2 = (sv.z == s), m3 = (sv.w == s);
            int cnt = m0 + m1 + m2 + m3;
            int x = cnt;                // wave inclusive scan
            #pragma unroll
            for (int o = 1; o < 64; o <<= 1) {
                int y = __shfl_up(x, o, 64);
                if (lane >= o) x += y;
            }
            if (lane == 63) wsum[w] = x;
            __syncthreads();            // wsum visible
            if (it == itLim && w == q) {
                int b = carry + (x - cnt);
                #pragma unroll
                for (int ww = 0; ww < 4; ++ww) if (ww < w) b += wsum[ww];
                int e = x - cnt;        // wave-local list offset
                if (m0) { lrow[e] = r0 + 0; lpos[e] = b; ++e; ++b; }
                if (m1) { lrow[e] = r0 + 1; lpos[e] = b; ++e; ++b; }
                if (m2) { lrow[e] = r0 + 2; lpos[e] = b; ++e; ++b; }
                if (m3) { lrow[e] = r0 + 3; lpos[e] = b; ++e; ++b; }
                if (lane == 63) nlist = x;
            }
            carry += wsum[0] + wsum[1] + wsum[2] + wsum[3];
            __syncthreads();            // reads done before next iter's writes
        }

        if (j == 31) {                  // full scan done: carry = s*PADS + cnt(s)
            if (tid == 0) writePtr[s] = carry;
            for (int slot = carry + tid; slot < s * PADS + PADS; slot += NTHR) {
                gIdx[slot] = -1; gLab[slot] = -2;
                posP[slot] = 0ull; negP[slot] = ~0ull;
            }
        }

        int nl = nlist;                 // gather my slice (expected ~16 rows)
        for (int li = w; li < nl; li += 4) {
            int row = lrow[li], p = lpos[li];
            float4 v = ((const float4*)(emb + (size_t)row * D))[lane];
            float sq = v.x * v.x + v.y * v.y + v.z * v.z + v.w * v.w;
            #pragma unroll
            for (int o = 32; o; o >>= 1) sq += __shfl_xor(sq, o, 64);
            us4 h;
            h.x = f2bf(v.x); h.y = f2bf(v.y); h.z = f2bf(v.z); h.w = f2bf(v.w);
            *(us4*)(gH + (size_t)p * D + lane * 4) = h;
            if (lane == 0) {
                gIdx[p] = row; gLab[p] = labels[row]; gSq[p] = sq;
                posP[p] = 0ull; negP[p] = ~0ull;    // real-slot init (unique owner)
            }
        }
    }

    grid.sync();

    // ---------- Phase B: mining ----------
    {
        int gw = bid * 4 + w;           // 2048 physical waves
        for (int lt = gw; lt < NTILES; lt += NBLK * 4) {
            int blk = lt >> 2, wv = lt & 3;
            int s2 = blk / 36;
            int rem = blk % 36;
            int rowt = rem / 3, cgp = rem % 3;
            int ctile = cgp * 4 + wv;
            mine_tile(s2, rowt, ctile, lane, gH, gIdx, gLab, gSq, writePtr, posP, negP);
        }
    }

    grid.sync();

    // ---------- Phase C: loss (block 0; emulates old 1024-thread order) ----------
    if (bid == 0) {
        float sum[4] = {0.f, 0.f, 0.f, 0.f}, cntv[4] = {0.f, 0.f, 0.f, 0.f};
        #pragma unroll
        for (int k = 0; k < 4; ++k) {
            for (int i = 0; i < 12; ++i) {
                int r = tid + 256 * k + 1024 * i;
                u64 p  = __hip_atomic_load(&posP[r], __ATOMIC_RELAXED, __HIP_MEMORY_SCOPE_AGENT);
                u64 nn = __hip_atomic_load(&negP[r], __ATOMIC_RELAXED, __HIP_MEMORY_SCOPE_AGENT);
                if (p != 0ull && nn != ~0ull) {
                    float dp = sqrtf(__uint_as_float((unsigned)(p >> 32)));
                    float dn = sqrtf(__uint_as_float((unsigned)(nn >> 32)));
                    sum[k] += fmaxf(dp - dn + MARGIN, 0.0f);
                    cntv[k] += 1.0f;
                }
            }
        }
        #pragma unroll
        for (int k = 0; k < 4; ++k)
            #pragma unroll
            for (int o = 32; o; o >>= 1) {
                sum[k]  += __shfl_xor(sum[k], o, 64);
                cntv[k] += __shfl_xor(cntv[k], o, 64);
            }
        __shared__ float ss[16], sc[16];
        if (lane == 0) {
            #pragma unroll
            for (int k = 0; k < 4; ++k) { ss[w + 4 * k] = sum[k]; sc[w + 4 * k] = cntv[k]; }
        }
        __syncthreads();
        if (tid == 0) {
            float S = 0.0f, C = 0.0f;
            #pragma unroll
            for (int i = 0; i < 16; ++i) { S += ss[i]; C += sc[i]; }
            out[0] = S / (C < 1.0f ? 1.0f : C);
        }
    }
}

// ================= fallback path: proven 4-kernel pipeline =================
__global__ void k_prep(const int* __restrict__ sbjv, int* __restrict__ pos,
                       int* __restrict__ writePtr, int* __restrict__ gIdx,
                       int* __restrict__ gLab, u64* __restrict__ posP,
                       u64* __restrict__ negP) {
    int s = blockIdx.x;
    int tid = threadIdx.x;
    int lane = tid & 63, w = tid >> 6;

    #pragma unroll
    for (int it = 0; it < 3; ++it) {
        int slot = s * PADS + it * 256 + tid;
        gIdx[slot] = -1;
        gLab[slot] = -2;
        posP[slot] = 0ull;
        negP[slot] = ~0ull;
    }

    __shared__ int wsum[4];
    __shared__ int carry;
    if (tid == 0) carry = s * PADS;
    __syncthreads();

    for (int iter = 0; iter < 8; ++iter) {
        int r0 = iter * 1024 + tid * 4;
        int4 sv = *(const int4*)(sbjv + r0);
        int m0 = (sv.x == s), m1 = (sv.y == s), m2 = (sv.z == s), m3 = (sv.w == s);
        int cnt = m0 + m1 + m2 + m3;
        int x = cnt;
        #pragma unroll
        for (int o = 1; o < 64; o <<= 1) {
            int y = __shfl_up(x, o, 64);
            if (lane >= o) x += y;
        }
        if (lane == 63) wsum[w] = x;
        __syncthreads();
        int b = carry + (x - cnt);
        #pragma unroll
        for (int ww = 0; ww < 4; ++ww) if (ww < w) b += wsum[ww];
        if (m0) pos[r0 + 0] = b++;
        if (m1) pos[r0 + 1] = b++;
        if (m2) pos[r0 + 2] = b++;
        if (m3) pos[r0 + 3] = b++;
        __syncthreads();
        if (tid == 0) carry += wsum[0] + wsum[1] + wsum[2] + wsum[3];
    }
    __syncthreads();
    if (tid == 0) writePtr[s] = carry;
}

__global__ void k_scatter(const float* __restrict__ emb, const int* __restrict__ labels,
                          const int* __restrict__ sbjv, const int* __restrict__ pos,
                          unsigned short* __restrict__ gH, int* __restrict__ gIdx,
                          int* __restrict__ gLab, float* __restrict__ gSq) {
    int wave = threadIdx.x >> 6;
    int lane = threadIdx.x & 63;
    int row = blockIdx.x * 4 + wave;
    const float4* e4 = (const float4*)(emb + (size_t)row * D);
    float4 v = e4[lane];
    float s = v.x * v.x + v.y * v.y + v.z * v.z + v.w * v.w;
    #pragma unroll
    for (int o = 32; o; o >>= 1) s += __shfl_xor(s, o, 64);
    int p = pos[row];
    us4 h;
    h.x = f2bf(v.x); h.y = f2bf(v.y); h.z = f2bf(v.z); h.w = f2bf(v.w);
    *(us4*)(gH + (size_t)p * D + lane * 4) = h;
    if (lane == 0) { gIdx[p] = row; gLab[p] = labels[row]; gSq[p] = s; }
}

__global__ __launch_bounds__(256) void k_mine(
        const unsigned short* __restrict__ gH, const int* __restrict__ gIdx,
        const int* __restrict__ gLab, const float* __restrict__ gSq,
        const int* __restrict__ writePtr,
        u64* __restrict__ posP, u64* __restrict__ negP) {
    int blk = blockIdx.x;
    int s   = blk / 36;
    int rem = blk % 36;
    int rowt = rem / 3, cgp = rem % 3;
    int tid  = threadIdx.x;
    int lane = tid & 63, w = tid >> 6;
    int ctile = cgp * 4 + w;
    mine_tile(s, rowt, ctile, lane, gH, gIdx, gLab, gSq, writePtr, posP, negP);
}

__global__ void k_loss(const u64* __restrict__ posP, const u64* __restrict__ negP,
                       float* __restrict__ out) {
    int tid = threadIdx.x;
    float sum = 0.0f, cnt = 0.0f;
    for (int r = tid; r < GN; r += 1024) {
        u64 p  = posP[r];
        u64 nn = negP[r];
        if (p != 0ull && nn != ~0ull) {
            float dp = sqrtf(__uint_as_float((unsigned)(p >> 32)));
            float dn = sqrtf(__uint_as_float((unsigned)(nn >> 32)));
            sum += fmaxf(dp - dn + MARGIN, 0.0f);
            cnt += 1.0f;
        }
    }
    #pragma unroll
    for (int o = 32; o; o >>= 1) {
        sum += __shfl_xor(sum, o, 64);
        cnt += __shfl_xor(cnt, o, 64);
    }
    __shared__ float ss[16], sc[16];
    int w = tid >> 6, lane = tid & 63;
    if (lane == 0) { ss[w] = sum; sc[w] = cnt; }
    __syncthreads();
    if (tid == 0) {
        float S = 0.0f, C = 0.0f;
        #pragma unroll
        for (int i = 0; i < 16; ++i) { S += ss[i]; C += sc[i]; }
        out[0] = S / (C < 1.0f ? 1.0f : C);
    }
}

extern "C" void kernel_launch(void* const* d_in, const int* in_sizes, int n_in,
                              void* d_out, int out_size, void* d_ws, size_t ws_size,
                              hipStream_t stream) {
    const float* emb  = (const float*)d_in[0];
    const int* labels = (const int*)d_in[1];
    const int* sbjv   = (const int*)d_in[2];
    float* out = (float*)d_out;

    char* ws = (char*)d_ws;
    unsigned short* gH = (unsigned short*)ws;                 // GN*D*2 = 6291456 B
    u64* posP = (u64*)(ws + 6291456);                         // GN*8 = 98304
    u64* negP = (u64*)(ws + 6389760);                         // GN*8 = 98304
    int* gIdx = (int*)(ws + 6488064);                         // GN*4 = 49152
    int* gLab = (int*)(ws + 6537216);
    float* gSq = (float*)(ws + 6586368);
    int* writePtr = (int*)(ws + 6635520);                     // 64 B
    int* pos = (int*)(ws + 6635584);                          // N*4 = 32768 (fallback only)

    void* args[] = {(void*)&emb, (void*)&labels, (void*)&sbjv, (void*)&gH,
                    (void*)&gIdx, (void*)&gLab, (void*)&gSq, (void*)&writePtr,
                    (void*)&posP, (void*)&negP, (void*)&out};
    hipError_t err = hipLaunchCooperativeKernel((const void*)k_fused, dim3(NBLK),
                                                dim3(NTHR), args, 0, stream);
    if (err != hipSuccess) {
        // fallback: proven 4-kernel pipeline (e.g. cooperative launch rejected)
        k_prep<<<NSUBJ, 256, 0, stream>>>(sbjv, pos, writePtr, gIdx, gLab, posP, negP);
        k_scatter<<<N / 4, 256, 0, stream>>>(emb, labels, sbjv, pos, gH, gIdx, gLab, gSq);
        k_mine<<<NSUBJ * 12 * 3, 256, 0, stream>>>(gH, gIdx, gLab, gSq, writePtr, posP, negP);
        k_loss<<<1, 1024, 0, stream>>>(posP, negP, out);
    }
}

// Round 2
// 109.055 us; speedup vs baseline: 2.3561x; 2.3561x over previous
//
#include <hip/hip_runtime.h>
#include <stdint.h>

#define N 8192
#define D 256
#define NSUBJ 16
#define PADS 768                 // padded slot per subject (mean 512, +11 sigma safe)
#define GN (NSUBJ * PADS)        // 12288 gathered rows
#define MARGIN 1.0f

typedef __attribute__((ext_vector_type(8))) short short8;   // 8 bf16 = 4 VGPRs (MFMA A/B frag)
typedef __attribute__((ext_vector_type(4))) float f32x4;    // MFMA C/D frag
typedef __attribute__((ext_vector_type(4))) unsigned short us4;
typedef unsigned long long u64;

__device__ __forceinline__ unsigned short f2bf(float x) {
    unsigned u = __float_as_uint(x);
    u += 0x7fffu + ((u >> 16) & 1u);
    return (unsigned short)(u >> 16);
}

// ---------------- ws layout ----------------
// ushort gH[GN*D]; u64 posP[GN]; u64 negP[GN]; int gIdx[GN]; int gLab[GN];
// float gSq[GN]; int writePtr[16]; int doneS[16]; int doneG; float partialS[16];
// float partialC[16]

// Kernel 1: fused prep + scatter.
//  blocks [0,2048): one wave per row. The wave computes the row's slot
//    deterministically (rank = #{i<row : sbj[i]==sbj[row]}) by scanning sbjv
//    (32 KB, L1-resident, coalesced int4) — bit-identical slot assignment to
//    the old two-kernel prep+scatter. Then gathers the row: fp32->bf16, sq
//    norm, metadata, and per-slot posP/negP init (unique owner, no race).
//  blocks [2048,2064): block 2048+s counts subject s, writes writePtr[s],
//    inits pad-slot gIdx/gLab (disjoint from real slots), zeroes doneS/doneG.
__global__ __launch_bounds__(256) void k_gather(
        const float* __restrict__ emb, const int* __restrict__ labels,
        const int* __restrict__ sbjv,
        unsigned short* __restrict__ gH, int* __restrict__ gIdx,
        int* __restrict__ gLab, float* __restrict__ gSq,
        int* __restrict__ writePtr, u64* __restrict__ posP,
        u64* __restrict__ negP, int* __restrict__ doneS, int* __restrict__ doneG) {
    int tid = threadIdx.x, lane = tid & 63, w = tid >> 6;
    const int4* s4 = (const int4*)sbjv;

    if (blockIdx.x >= 2048) {               // count / init block for subject s
        int s = blockIdx.x - 2048;
        int c = 0;
        #pragma unroll
        for (int i = 0; i < 8; ++i) {       // 256 thr x 8 int4 = 8192 ints
            int4 v = s4[tid + 256 * i];
            c += (v.x == s) + (v.y == s) + (v.z == s) + (v.w == s);
        }
        #pragma unroll
        for (int o = 32; o; o >>= 1) c += __shfl_xor(c, o, 64);
        __shared__ int wc[4];
        if (lane == 0) wc[w] = c;
        __syncthreads();
        int cnt = wc[0] + wc[1] + wc[2] + wc[3];
        if (tid == 0) {
            writePtr[s] = s * PADS + cnt;
            doneS[s] = 0;
            if (s == 0) *doneG = 0;
        }
        // pad slots [cnt, PADS): only gIdx/gLab are ever read by mining
        for (int sl = cnt + tid; sl < PADS; sl += 256) {
            gIdx[s * PADS + sl] = -1;
            gLab[s * PADS + sl] = -2;
        }
        return;
    }

    // ---- gather block: 4 rows, one wave each ----
    int row = blockIdx.x * 4 + w;
    int s = sbjv[row];
    // deterministic rank: count of same-subject rows before this one.
    int nfull = row >> 8;                   // full 256-int chunks
    int c = 0;
    for (int ch = 0; ch < nfull; ++ch) {
        int4 v = s4[ch * 64 + lane];
        c += (v.x == s) + (v.y == s) + (v.z == s) + (v.w == s);
    }
    {   // tail chunk (partially valid); max int4 index = 2047, in-bounds
        int4 v = s4[nfull * 64 + lane];
        int base = nfull * 256 + lane * 4;
        c += (base + 0 < row && v.x == s) + (base + 1 < row && v.y == s) +
             (base + 2 < row && v.z == s) + (base + 3 < row && v.w == s);
    }
    #pragma unroll
    for (int o = 32; o; o >>= 1) c += __shfl_xor(c, o, 64);
    int p = s * PADS + c;                   // wave-uniform slot

    float4 v = ((const float4*)(emb + (size_t)row * D))[lane];
    float sq = v.x * v.x + v.y * v.y + v.z * v.z + v.w * v.w;
    #pragma unroll
    for (int o = 32; o; o >>= 1) sq += __shfl_xor(sq, o, 64);
    us4 h;
    h.x = f2bf(v.x); h.y = f2bf(v.y); h.z = f2bf(v.z); h.w = f2bf(v.w);
    *(us4*)(gH + (size_t)p * D + lane * 4) = h;
    if (lane == 0) {
        gIdx[p] = row; gLab[p] = labels[row]; gSq[p] = sq;
        posP[p] = 0ull; negP[p] = ~0ull;    // unique owner, no race
    }
}

// mining body for one 64x64 tile (one wave). Identical math to the proven
// k_mine (bit-identical packed keys).
__device__ __forceinline__ void mine_tile(
        int s, int rowt, int ctile, int lane,
        const unsigned short* __restrict__ gH, const int* __restrict__ gIdx,
        const int* __restrict__ gLab, const float* __restrict__ gSq,
        const int* __restrict__ writePtr,
        u64* __restrict__ posP, u64* __restrict__ negP) {
    int quad = lane >> 4, l15 = lane & 15;
    int base = s * PADS;
    int cntS = writePtr[s] - base;
    if (rowt * 64 >= cntS || ctile * 64 >= cntS) return;   // wave-uniform exit
    int i0 = base + rowt * 64;
    int j0 = base + ctile * 64;

    int labc[4], idxc[4];
    float sqc[4];
    #pragma unroll
    for (int nt = 0; nt < 4; ++nt) {
        int cidx = j0 + nt * 16 + l15;
        labc[nt] = gLab[cidx]; idxc[nt] = gIdx[cidx]; sqc[nt] = gSq[cidx];
    }
    int labr[4][4], idxr[4][4];
    float sqr[4][4];
    #pragma unroll
    for (int mt = 0; mt < 4; ++mt)
        #pragma unroll
        for (int rg = 0; rg < 4; ++rg) {
            int r = i0 + mt * 16 + quad * 4 + rg;
            labr[mt][rg] = gLab[r]; idxr[mt][rg] = gIdx[r]; sqr[mt][rg] = gSq[r];
        }

    f32x4 acc[4][4];
    #pragma unroll
    for (int mt = 0; mt < 4; ++mt)
        #pragma unroll
        for (int nt = 0; nt < 4; ++nt) {
            f32x4 z = {0.f, 0.f, 0.f, 0.f};
            acc[mt][nt] = z;
        }

    #pragma unroll 2
    for (int kb = 0; kb < 8; ++kb) {
        int koff = kb * 32 + quad * 8;
        short8 a[4], b[4];
        #pragma unroll
        for (int mt = 0; mt < 4; ++mt)
            a[mt] = *(const short8*)(gH + (size_t)(i0 + mt * 16 + l15) * D + koff);
        #pragma unroll
        for (int nt = 0; nt < 4; ++nt)
            b[nt] = *(const short8*)(gH + (size_t)(j0 + nt * 16 + l15) * D + koff);
        #pragma unroll
        for (int mt = 0; mt < 4; ++mt)
            #pragma unroll
            for (int nt = 0; nt < 4; ++nt)
                acc[mt][nt] = __builtin_amdgcn_mfma_f32_16x16x32_bf16(
                    a[mt], b[nt], acc[mt][nt], 0, 0, 0);
    }

    // ---- mining epilogue: C layout col = lane&15, row = quad*4 + reg ----
    #pragma unroll
    for (int mt = 0; mt < 4; ++mt) {
        u64 bp[4], bn[4];
        #pragma unroll
        for (int rg = 0; rg < 4; ++rg) { bp[rg] = 0ull; bn[rg] = ~0ull; }
        #pragma unroll
        for (int nt = 0; nt < 4; ++nt) {
            int lc = labc[nt], ic = idxc[nt];
            float sc = sqc[nt];
            f32x4 v = acc[mt][nt];
            #pragma unroll
            for (int rg = 0; rg < 4; ++rg) {
                float d2 = fmaxf(sqr[mt][rg] + sc - 2.0f * v[rg], 0.0f);
                u64 db = ((u64)__float_as_uint(d2)) << 32;
                if (lc == labr[mt][rg] && ic != idxr[mt][rg] && ic >= 0) {
                    u64 pk = db | (u64)(unsigned)(~(unsigned)ic);
                    if (pk > bp[rg]) bp[rg] = pk;
                }
                if (lc != labr[mt][rg] && ic >= 0) {
                    u64 nk = db | (u64)(unsigned)ic;
                    if (nk < bn[rg]) bn[rg] = nk;
                }
            }
        }
        #pragma unroll
        for (int o = 1; o < 16; o <<= 1) {
            #pragma unroll
            for (int rg = 0; rg < 4; ++rg) {
                u64 pp = __shfl_xor(bp[rg], o, 64);
                if (pp > bp[rg]) bp[rg] = pp;
                u64 qq = __shfl_xor(bn[rg], o, 64);
                if (qq < bn[rg]) bn[rg] = qq;
            }
        }
        if (l15 == 0) {
            #pragma unroll
            for (int rg = 0; rg < 4; ++rg) {
                int r = i0 + mt * 16 + quad * 4 + rg;
                if (bp[rg]) atomicMax(&posP[r], bp[rg]);
                if (bn[rg] != ~0ull) atomicMin(&negP[r], bn[rg]);
            }
        }
    }
}

// Kernel 2: mining + distributed loss.
//  grid 16 subjects x 36 tile-blocks. After mining, every block increments
//  doneS[s]; the 36th finisher of subject s reduces that subject's slots into
//  partialS/partialC[s] (deterministic grouping), then the 16th subject
//  finisher (doneG) sums the 16 partials in fixed order -> out[0].
//  No cooperative launch, no grid.sync (R1 lesson: grid.sync ~80us on MI355X).
__global__ __launch_bounds__(256) void k_mine(
        const unsigned short* __restrict__ gH, const int* __restrict__ gIdx,
        const int* __restrict__ gLab, const float* __restrict__ gSq,
        const int* __restrict__ writePtr,
        u64* __restrict__ posP, u64* __restrict__ negP,
        int* __restrict__ doneS, int* __restrict__ doneG,
        float* __restrict__ partialS, float* __restrict__ partialC,
        float* __restrict__ out) {
    int blk = blockIdx.x;
    int s   = blk / 36;
    int rem = blk % 36;
    int rowt = rem / 3, cgp = rem % 3;
    int tid  = threadIdx.x;
    int lane = tid & 63, w = tid >> 6;
    int ctile = cgp * 4 + w;

    mine_tile(s, rowt, ctile, lane, gH, gIdx, gLab, gSq, writePtr, posP, negP);

    // ---- per-subject completion ----
    __syncthreads();
    __shared__ int role;
    if (tid == 0) {
        __threadfence();                        // release this block's atomics
        role = (atomicAdd(&doneS[s], 1) == 35); // last of 36 subject-s blocks
    }
    __syncthreads();
    if (!role) return;

    // ---- subject-s loss partial (deterministic grouping) ----
    __threadfence();
    int base = s * PADS;
    int cntS = writePtr[s] - base;
    float S = 0.f, C = 0.f;
    #pragma unroll
    for (int k = 0; k < 3; ++k) {
        int local = tid + 256 * k;
        if (local < cntS) {
            u64 p  = __hip_atomic_load(&posP[base + local], __ATOMIC_RELAXED,
                                       __HIP_MEMORY_SCOPE_AGENT);
            u64 nn = __hip_atomic_load(&negP[base + local], __ATOMIC_RELAXED,
                                       __HIP_MEMORY_SCOPE_AGENT);
            if (p != 0ull && nn != ~0ull) {
                float dp = sqrtf(__uint_as_float((unsigned)(p >> 32)));
                float dn = sqrtf(__uint_as_float((unsigned)(nn >> 32)));
                S += fmaxf(dp - dn + MARGIN, 0.0f);
                C += 1.0f;
            }
        }
    }
    #pragma unroll
    for (int o = 32; o; o >>= 1) {
        S += __shfl_xor(S, o, 64);
        C += __shfl_xor(C, o, 64);
    }
    __shared__ float ssS[4], ssC[4];
    if (lane == 0) { ssS[w] = S; ssC[w] = C; }
    __syncthreads();
    if (tid == 0) {
        float PS = ssS[0] + ssS[1] + ssS[2] + ssS[3];
        float PC = ssC[0] + ssC[1] + ssC[2] + ssC[3];
        __hip_atomic_store(&partialS[s], PS, __ATOMIC_RELAXED, __HIP_MEMORY_SCOPE_AGENT);
        __hip_atomic_store(&partialC[s], PC, __ATOMIC_RELAXED, __HIP_MEMORY_SCOPE_AGENT);
        __threadfence();
        if (atomicAdd(doneG, 1) == 15) {        // last subject finisher
            __threadfence();
            float TS = 0.f, TC = 0.f;
            #pragma unroll
            for (int s2 = 0; s2 < NSUBJ; ++s2) {
                TS += __hip_atomic_load(&partialS[s2], __ATOMIC_RELAXED,
                                        __HIP_MEMORY_SCOPE_AGENT);
                TC += __hip_atomic_load(&partialC[s2], __ATOMIC_RELAXED,
                                        __HIP_MEMORY_SCOPE_AGENT);
            }
            out[0] = TS / (TC < 1.0f ? 1.0f : TC);
        }
    }
}

extern "C" void kernel_launch(void* const* d_in, const int* in_sizes, int n_in,
                              void* d_out, int out_size, void* d_ws, size_t ws_size,
                              hipStream_t stream) {
    const float* emb  = (const float*)d_in[0];
    const int* labels = (const int*)d_in[1];
    const int* sbjv   = (const int*)d_in[2];
    float* out = (float*)d_out;

    char* ws = (char*)d_ws;
    unsigned short* gH = (unsigned short*)ws;                 // GN*D*2 = 6291456 B
    u64* posP     = (u64*)(ws + 6291456);                     // GN*8 = 98304
    u64* negP     = (u64*)(ws + 6389760);                     // GN*8 = 98304
    int* gIdx     = (int*)(ws + 6488064);                     // GN*4 = 49152
    int* gLab     = (int*)(ws + 6537216);                     // GN*4
    float* gSq    = (float*)(ws + 6586368);                   // GN*4
    int* writePtr = (int*)(ws + 6635520);                     // 64 B
    int* doneS    = (int*)(ws + 6635584);                     // 64 B
    int* doneG    = (int*)(ws + 6635648);                     // 64 B
    float* partialS = (float*)(ws + 6635712);                 // 64 B
    float* partialC = (float*)(ws + 6635776);                 // 64 B

    k_gather<<<2064, 256, 0, stream>>>(emb, labels, sbjv, gH, gIdx, gLab, gSq,
                                       writePtr, posP, negP, doneS, doneG);
    k_mine<<<NSUBJ * 12 * 3, 256, 0, stream>>>(gH, gIdx, gLab, gSq, writePtr,
                                               posP, negP, doneS, doneG,
                                               partialS, partialC, out);
}